// Round 5
// baseline (721.745 us; speedup 1.0000x reference)
//
#include <hip/hip_runtime.h>
#include <hip/hip_bf16.h>

typedef short bf16x8 __attribute__((ext_vector_type(8)));
typedef float f32x4 __attribute__((ext_vector_type(4)));

constexpr int NN = 100000;           // nodes
constexpr int NE = 1600000;          // edges
constexpr int HH = 128;              // hidden
constexpr int NR = 8;                // relations
constexpr int NBIN = 782;            // ceil(NN/128) bins by dst>>7
constexpr int CAPB = 6144;           // max edges per bin on the LDS fast path

__device__ __forceinline__ unsigned short f2bf(float f) {
    unsigned b = __float_as_uint(f);
    b += 0x7fffu + ((b >> 16) & 1u);       // round-to-nearest-even
    return (unsigned short)(b >> 16);
}

// ---- fused convert: blocks [0,1152): W transpose; rest: x ----
// Wt[L][s][f][·] (bf16) from fp32 W[d][f], stored CHUNK-SWIZZLED: within each
// 256B row, 16B chunk c lands at c ^ (f&7)  (bank-conflict-free ds_read_b128
// while keeping global_load_lds linear — both-sides swizzle).
__global__ void convertWX(const float* __restrict__ Wr0, const float* __restrict__ Wq0,
                          const float* __restrict__ Wr1, const float* __restrict__ Wq1,
                          unsigned short* __restrict__ Wt,
                          const int* __restrict__ node_idx,
                          const float* __restrict__ emb,
                          unsigned* __restrict__ xb32) {
    if (blockIdx.x < 1152) {           // 1152*256 = 294912 = 2*9*128*128
        int o = blockIdx.x * 256 + threadIdx.x;
        int L = o / 147456;
        int rem = o - L * 147456;
        int s = rem >> 14;
        int p = rem & 16383;
        int f = p >> 7;
        int d = p & 127;
        const float* Wq = L ? Wq1 : Wq0;
        const float* Wr = L ? Wr1 : Wr0;
        float v = (s == 0) ? Wq[d * 128 + f] : Wr[((s - 1) * 128 + d) * 128 + f];
        int cs = (d >> 3) ^ (f & 7);                     // swizzled 16B-chunk idx
        Wt[(o & ~127) | (cs << 3) | (d & 7)] = f2bf(v);
    } else {
        int i = (blockIdx.x - 1152) * 256 + threadIdx.x;
        if (i >= NN * 64) return;
        int n = i >> 6, dp = i & 63;
        int row = node_idx[n];
        float2 v = *((const float2*)(emb + (size_t)row * HH) + dp);
        xb32[(size_t)n * 64 + dp] = (unsigned)f2bf(v.x) | ((unsigned)f2bf(v.y) << 16);
    }
}

// ---- pass A1: per-bin edge counts (LDS histogram -> global merge) ----
__global__ __launch_bounds__(256) void binCount(const int* __restrict__ edst,
                                                unsigned* __restrict__ binCounts) {
    __shared__ unsigned hist[NBIN];
    for (int i = threadIdx.x; i < NBIN; i += 256) hist[i] = 0;
    __syncthreads();
    int stride = gridDim.x * 256;
    for (int e = blockIdx.x * 256 + threadIdx.x; e < NE; e += stride)
        atomicAdd(&hist[((unsigned)edst[e]) >> 7], 1u);
    __syncthreads();
    for (int i = threadIdx.x; i < NBIN; i += 256)
        if (hist[i]) atomicAdd(&binCounts[i], hist[i]);
}

// ---- pass A2: exclusive scan of 782 bin counts; init cursors ----
__global__ void binScan(const unsigned* __restrict__ binCounts,
                        unsigned* __restrict__ binStarts,
                        unsigned* __restrict__ binCursor) {
    __shared__ unsigned sh[1024];
    int tid = threadIdx.x;
    unsigned v = (tid < NBIN) ? binCounts[tid] : 0u;
    sh[tid] = v;
    __syncthreads();
    for (int ofs = 1; ofs < 1024; ofs <<= 1) {
        unsigned t = (tid >= ofs) ? sh[tid - ofs] : 0u;
        __syncthreads();
        sh[tid] += t;
        __syncthreads();
    }
    if (tid < NBIN) {
        unsigned s = sh[tid] - v;
        binStarts[tid] = s;
        binCursor[tid] = s;
    }
    if (tid == 0) binStarts[NBIN] = NE;
}

// ---- pass A3: scatter edges into bins (block-chunked -> L2-local writes) ----
// payload: src(17b) | rel(3b)<<17 | dstlow(7b)<<20
__global__ __launch_bounds__(256) void binScatter(
        const int* __restrict__ esrc, const int* __restrict__ edst,
        const int* __restrict__ etype, unsigned* __restrict__ binCursor,
        unsigned* __restrict__ binned) {
    __shared__ unsigned hist[NBIN];
    __shared__ unsigned cur[NBIN];
    for (int i = threadIdx.x; i < NBIN; i += 256) hist[i] = 0;
    __syncthreads();
    int per = (NE + gridDim.x - 1) / gridDim.x;
    int lo = blockIdx.x * per;
    int hi = lo + per; if (hi > NE) hi = NE;
    for (int e = lo + threadIdx.x; e < hi; e += 256)
        atomicAdd(&hist[((unsigned)edst[e]) >> 7], 1u);
    __syncthreads();
    for (int i = threadIdx.x; i < NBIN; i += 256) {
        unsigned c = hist[i];
        cur[i] = c ? atomicAdd(&binCursor[i], c) : 0u;
    }
    __syncthreads();
    for (int e = lo + threadIdx.x; e < hi; e += 256) {
        unsigned d = (unsigned)edst[e];
        unsigned b = d >> 7;
        unsigned pos = atomicAdd(&cur[b], 1u);
        binned[pos] = (unsigned)esrc[e] | (((unsigned)etype[e]) << 17) |
                      ((d & 127u) << 20);
    }
}

// ---- pass B: per-bin LDS sort by (dstlow,rel); emit payload + CSR starts ----
// payload: src(17b)<<3 | rel(3b) | deg(12b)<<20
__global__ __launch_bounds__(256) void binSort(
        const unsigned* __restrict__ binStarts, const unsigned* __restrict__ binned,
        unsigned* __restrict__ epk, unsigned* __restrict__ starts) {
    __shared__ unsigned hist[1024];
    __shared__ unsigned scn[1024];
    __shared__ unsigned cnts[1024];
    __shared__ unsigned part[256];
    __shared__ unsigned buf[CAPB];
    __shared__ unsigned outb[CAPB];
    int bin = blockIdx.x;
    int tid = threadIdx.x;
    unsigned base = binStarts[bin];
    int cnt = (int)(binStarts[bin + 1] - base);

    for (int i = tid; i < 1024; i += 256) hist[i] = 0;
    __syncthreads();
    for (int i = tid; i < cnt; i += 256) {
        unsigned p = binned[base + i];
        if (i < CAPB) buf[i] = p;
        atomicAdd(&hist[(p >> 17) & 0x3ffu], 1u);   // key = dstlow*8 + rel
    }
    __syncthreads();
    // exclusive scan of hist[1024]
    unsigned h4[4], tsum = 0;
#pragma unroll
    for (int j = 0; j < 4; ++j) { h4[j] = hist[tid * 4 + j]; tsum += h4[j]; }
    part[tid] = tsum;
    __syncthreads();
    for (int ofs = 1; ofs < 256; ofs <<= 1) {
        unsigned t = (tid >= ofs) ? part[tid - ofs] : 0u;
        __syncthreads();
        part[tid] += t;
        __syncthreads();
    }
    unsigned run = part[tid] - tsum;
#pragma unroll
    for (int j = 0; j < 4; ++j) { scn[tid * 4 + j] = run; run += h4[j]; }
    __syncthreads();
    // global CSR starts (starts[node*8+rel] == base + scn[key]); keep counts
    for (int i = tid; i < 1024; i += 256) {
        starts[(size_t)bin * 1024 + i] = base + scn[i];
        cnts[i] = hist[i];                           // segment length for deg
        hist[i] = scn[i];                            // reuse hist as cursor
    }
    __syncthreads();
    if (cnt <= CAPB) {
        for (int i = tid; i < cnt; i += 256) {
            unsigned p = buf[i];
            unsigned key = (p >> 17) & 0x3ffu;
            unsigned pos = atomicAdd(&hist[key], 1u);
            unsigned deg = cnts[key]; if (deg > 4095u) deg = 4095u;
            outb[pos] = ((p & 0x1ffffu) << 3) | (key & 7u) | (deg << 20);
        }
        __syncthreads();
        for (int i = tid; i < cnt; i += 256) epk[base + i] = outb[i];
    } else {                                          // never expected; safety
        for (int i = tid; i < cnt; i += 256) {
            unsigned p = binned[base + i];
            unsigned key = (p >> 17) & 0x3ffu;
            unsigned pos = atomicAdd(&hist[key], 1u);
            unsigned deg = cnts[key]; if (deg > 4095u) deg = 4095u;
            epk[base + pos] = ((p & 0x1ffffu) << 3) | (key & 7u) | (deg << 20);
        }
    }
}

// ---- FUSED layer: out[n] = relu(b + x[n]@W_root + sum_r mean_{N_r(n)} x @ W_r)
// y intermediate ELIMINATED. Block = 64 dst nodes, 256 threads (4 waves).
// Per K-tile s: s=0 A-tile = x rows (root); s>0 A-tile = gathered per-relation
// means built in LDS from L2/L3-resident x. W LDS double-buffered (proven).
// acc accumulates across all 9 K-tiles; epilogue adds bias, relu, stores.
// OUT32=0: bf16 out via LDS-transpose (row-coalesced). OUT32=1: fp32 out.
template<int OUT32>
__global__ __launch_bounds__(256, 2) void rgcnFused(
        const unsigned* __restrict__ xin,        // [NN][64] bf16-pair dwords
        const unsigned short* __restrict__ Wt,   // swizzled [9][128][128]
        const unsigned* __restrict__ starts, const unsigned* __restrict__ epk,
        const float* __restrict__ bias,
        unsigned* __restrict__ outB, float* __restrict__ outF) {
    typedef __attribute__((address_space(3))) unsigned lds_u32_t;
    typedef const __attribute__((address_space(1))) unsigned glb_u32_t;
    __shared__ __align__(16) unsigned short Wl[2][16384];   // 64 KB W double-buf
    __shared__ __align__(16) unsigned Agg[4096];            // 16 KB A-tile / epilogue

    int tid = threadIdx.x;
    int wid = tid >> 6, lane = tid & 63;
    int quad = lane >> 4, l16 = lane & 15;
    int wr = wid >> 1, wc = wid & 1;   // wr: node half (32), wc: channel half (64)
    int node0 = blockIdx.x * 64;
    int sw = l16 & 7;

    auto prefetch = [&](int s, int b) {
        const char* gs = (const char*)Wt + (size_t)s * 32768 + wid * 1024 + lane * 16;
        char* ls = (char*)&Wl[b][0] + wid * 1024;
#pragma unroll
        for (int j = 0; j < 8; ++j)
            __builtin_amdgcn_global_load_lds((glb_u32_t*)(const void*)(gs + j * 4096),
                                             (lds_u32_t*)(void*)(ls + j * 4096),
                                             16, 0, 0);
    };

    prefetch(0, 0);

    f32x4 acc[2][4];
#pragma unroll
    for (int nt = 0; nt < 2; ++nt)
#pragma unroll
        for (int ft = 0; ft < 4; ++ft) acc[nt][ft] = (f32x4){0.f, 0.f, 0.f, 0.f};

    for (int s = 0; s < 9; ++s) {
        __syncthreads();               // prev MFMA done with Agg + W[(s+1)&1]
        if (s < 8) prefetch(s + 1, (s + 1) & 1);

        if (s == 0) {
            // root A-tile: copy x rows with chunk swizzle
#pragma unroll
            for (int p = 0; p < 4; ++p) {
                int i = p * 16 + (tid >> 4);
                int c = tid & 15;
                int nd = node0 + i; nd = nd < NN ? nd : NN - 1;
                uint4 v = *((const uint4*)(xin + (size_t)nd * 64) + c);
                *(uint4*)((char*)Agg + i * 256 + ((c ^ (i & 7)) << 4)) = v;
            }
        } else {
            // gather A-tile: mean_{j in N_r(node)} x_j, wave handles 16 nodes
            int r = s - 1;
            int ndl = node0 + wid * 16 + (lane & 15);
            if (ndl > NN - 1) ndl = NN - 1;
            unsigned bv = starts[(size_t)ndl * 8 + r + ((lane >> 4) & 1)];
            unsigned s0a[16]; int da[16];
#pragma unroll
            for (int t = 0; t < 16; ++t) {
                unsigned a = (unsigned)__builtin_amdgcn_readlane((int)bv, t);
                unsigned b = (unsigned)__builtin_amdgcn_readlane((int)bv, t + 16);
                s0a[t] = a; da[t] = (int)(b - a);
            }
            float axv[16], ayv[16];
#pragma unroll
            for (int t = 0; t < 16; ++t) { axv[t] = 0.f; ayv[t] = 0.f; }
#pragma unroll
            for (int j = 0; j < 4; ++j) {       // j-major: 16 loads in flight
                unsigned qv[16];
#pragma unroll
                for (int t = 0; t < 16; ++t)
                    if (j < da[t]) {
                        unsigned pk = epk[s0a[t] + j];          // scalar load
                        qv[t] = xin[(size_t)((pk >> 3) & 0x1ffffu) * 64 + lane];
                    }
#pragma unroll
                for (int t = 0; t < 16; ++t)
                    if (j < da[t]) {
                        axv[t] += __uint_as_float(qv[t] << 16);
                        ayv[t] += __uint_as_float(qv[t] & 0xffff0000u);
                    }
            }
#pragma unroll
            for (int t = 0; t < 16; ++t) {      // rare deg>4 tails
                int e1 = (int)s0a[t] + da[t];
                for (int e = (int)s0a[t] + 4; e < e1; ++e) {
                    unsigned pk = epk[e];
                    unsigned q = xin[(size_t)((pk >> 3) & 0x1ffffu) * 64 + lane];
                    axv[t] += __uint_as_float(q << 16);
                    ayv[t] += __uint_as_float(q & 0xffff0000u);
                }
            }
#pragma unroll
            for (int t = 0; t < 16; ++t) {
                float nrm = da[t] > 0 ? __builtin_amdgcn_rcpf((float)da[t]) : 0.f;
                float lo = axv[t] * nrm, hi = ayv[t] * nrm;
                unsigned dw;
                asm("v_cvt_pk_bf16_f32 %0, %1, %2" : "=v"(dw) : "v"(lo), "v"(hi));
                int i = wid * 16 + t;
                *(unsigned*)((char*)Agg + i * 256 +
                             ((((lane >> 2) ^ (t & 7)) << 4) | ((lane & 3) << 2))) = dw;
            }
        }
        __syncthreads();               // A ready; W(s) + prefetch(s+1) drained

        const char* Bb = (const char*)&Wl[s & 1][0];
        const char* Ab = (const char*)Agg;
#pragma unroll
        for (int kt = 0; kt < 4; ++kt) {
            bf16x8 bw[4], axx[2];
#pragma unroll
            for (int ft = 0; ft < 4; ++ft)
                bw[ft] = *(const bf16x8*)(Bb + (wc * 64 + ft * 16 + l16) * 256 +
                                          (((kt * 4 + quad) ^ sw) << 4));
#pragma unroll
            for (int nt = 0; nt < 2; ++nt)
                axx[nt] = *(const bf16x8*)(Ab + (wr * 32 + nt * 16 + l16) * 256 +
                                           (((kt * 4 + quad) ^ sw) << 4));
#pragma unroll
            for (int nt = 0; nt < 2; ++nt)
#pragma unroll
                for (int ft = 0; ft < 4; ++ft)
                    acc[nt][ft] = __builtin_amdgcn_mfma_f32_16x16x32_bf16(
                        bw[ft], axx[nt], acc[nt][ft], 0, 0, 0);
        }
    }

    // bias: channel = wc*64 + ft*16 + quad*4 + rg
    float bvv[4][4];
#pragma unroll
    for (int ft = 0; ft < 4; ++ft)
#pragma unroll
        for (int rg = 0; rg < 4; ++rg)
            bvv[ft][rg] = bias[wc * 64 + ft * 16 + quad * 4 + rg];

    if (!OUT32) {
        // bf16 out via LDS transpose (reuse Agg: 64 rows x 256 B)
        __syncthreads();               // last MFMA done reading Agg
#pragma unroll
        for (int nt = 0; nt < 2; ++nt) {
            int rT = wr * 32 + nt * 16 + l16;
#pragma unroll
            for (int ft = 0; ft < 4; ++ft) {
                float v0 = acc[nt][ft][0] + bvv[ft][0]; v0 = v0 > 0.f ? v0 : 0.f;
                float v1 = acc[nt][ft][1] + bvv[ft][1]; v1 = v1 > 0.f ? v1 : 0.f;
                float v2 = acc[nt][ft][2] + bvv[ft][2]; v2 = v2 > 0.f ? v2 : 0.f;
                float v3 = acc[nt][ft][3] + bvv[ft][3]; v3 = v3 > 0.f ? v3 : 0.f;
                unsigned d0, d1;
                asm("v_cvt_pk_bf16_f32 %0, %1, %2" : "=v"(d0) : "v"(v0), "v"(v1));
                asm("v_cvt_pk_bf16_f32 %0, %1, %2" : "=v"(d1) : "v"(v2), "v"(v3));
                int slot = wc * 16 + ft * 4 + quad;          // 8-B slots, 32/row
                *(uint2*)((char*)Agg + rT * 256 +
                          ((slot ^ ((rT & 7) << 2)) << 3)) = make_uint2(d0, d1);
            }
        }
        __syncthreads();
#pragma unroll
        for (int pp = 0; pp < 4; ++pp) {
            int idx = pp * 256 + tid;          // 64 rows x 16 chunks(16B)
            int rT = idx >> 4, c16 = idx & 15;
            uint4 v = *(const uint4*)((char*)Agg + rT * 256 +
                                      (((c16 * 2) ^ ((rT & 7) << 2)) << 3));
            int node = node0 + rT;
            if (node < NN) *((uint4*)(outB + (size_t)node * 64) + c16) = v;
        }
    } else {
        // fp32 out via LDS transpose in two 32-row halves (Agg: 32 x 512 B)
#pragma unroll
        for (int h = 0; h < 2; ++h) {
            __syncthreads();
            if (wr == h) {
#pragma unroll
                for (int nt = 0; nt < 2; ++nt) {
                    int rloc = nt * 16 + l16;
#pragma unroll
                    for (int ft = 0; ft < 4; ++ft) {
                        f32x4 v;
#pragma unroll
                        for (int rg = 0; rg < 4; ++rg) {
                            float u = acc[nt][ft][rg] + bvv[ft][rg];
                            v[rg] = u > 0.f ? u : 0.f;
                        }
                        int c32 = wc * 16 + ft * 4 + quad;   // 16-B chunks, 32/row
                        *(f32x4*)((char*)Agg + rloc * 512 +
                                  ((c32 ^ ((rloc & 7) << 2)) << 4)) = v;
                    }
                }
            }
            __syncthreads();
#pragma unroll
            for (int pp = 0; pp < 4; ++pp) {
                int idx = pp * 256 + tid;      // 32 rows x 32 chunks
                int rloc = idx >> 5, c32 = idx & 31;
                f32x4 v = *(const f32x4*)((char*)Agg + rloc * 512 +
                                          ((c32 ^ ((rloc & 7) << 2)) << 4));
                int node = node0 + h * 32 + rloc;
                if (node < NN)
                    *(f32x4*)(outF + (size_t)node * HH + c32 * 4) = v;
            }
        }
    }
}

extern "C" void kernel_launch(void* const* d_in, const int* in_sizes, int n_in,
                              void* d_out, int out_size, void* d_ws, size_t ws_size,
                              hipStream_t stream) {
    const int* node_idx = (const int*)d_in[0];
    const int* eidx     = (const int*)d_in[1];
    const int* etype    = (const int*)d_in[2];
    const float* emb    = (const float*)d_in[3];
    const float* Wr0    = (const float*)d_in[4];
    const float* Wq0    = (const float*)d_in[5];
    const float* b0     = (const float*)d_in[6];
    const float* Wr1    = (const float*)d_in[7];
    const float* Wq1    = (const float*)d_in[8];
    const float* b1     = (const float*)d_in[9];
    const int* esrc = eidx;
    const int* edst = eidx + NE;

    char* ws = (char*)d_ws;
    size_t off = 0;
    auto alloc = [&](size_t bytes) -> void* {
        void* p = ws + off;
        off = (off + bytes + 255) & ~(size_t)255;
        return p;
    };
    // Workspace ~68 MB (y eliminated; ping-pong x buffers instead).
    unsigned* binCounts = (unsigned*)alloc((size_t)NBIN * 4);
    unsigned* binStarts = (unsigned*)alloc((size_t)(NBIN + 1) * 4);
    unsigned* binCursor = (unsigned*)alloc((size_t)NBIN * 4);
    unsigned* starts    = (unsigned*)alloc((size_t)NBIN * 1024 * 4);   // 3.2 MB CSR
    unsigned* epk       = (unsigned*)alloc((size_t)NE * 4);
    unsigned* xA        = (unsigned*)alloc((size_t)NN * 64 * 4);       // 25.6 MB
    unsigned* xB        = (unsigned*)alloc((size_t)NN * 64 * 4);       // 25.6 MB
    unsigned short* Wt  = (unsigned short*)alloc((size_t)2 * 9 * 16384 * 2);
    unsigned* binned    = (unsigned*)alloc((size_t)NE * 4);            // 6.4 MB
    (void)ws_size; (void)n_in; (void)in_sizes; (void)out_size;

    hipMemsetAsync(binCounts, 0, (size_t)NBIN * 4, stream);
    convertWX<<<1152 + (NN * 64 + 255) / 256, 256, 0, stream>>>(
        Wr0, Wq0, Wr1, Wq1, Wt, node_idx, emb, xA);
    binCount<<<256, 256, 0, stream>>>(edst, binCounts);
    binScan<<<1, 1024, 0, stream>>>(binCounts, binStarts, binCursor);
    binScatter<<<128, 256, 0, stream>>>(esrc, edst, etype, binCursor, binned);
    binSort<<<NBIN, 256, 0, stream>>>(binStarts, binned, epk, starts);

    int nblk = (NN + 63) / 64;
    rgcnFused<0><<<nblk, 256, 0, stream>>>(xA, Wt, starts, epk, b0, xB, nullptr);
    rgcnFused<1><<<nblk, 256, 0, stream>>>(xB, Wt + 147456, starts, epk, b1,
                                           nullptr, (float*)d_out);
}

// Round 6
// 500.820 us; speedup vs baseline: 1.4411x; 1.4411x over previous
//
#include <hip/hip_runtime.h>
#include <hip/hip_bf16.h>

typedef short bf16x8 __attribute__((ext_vector_type(8)));
typedef float f32x4 __attribute__((ext_vector_type(4)));

constexpr int NN = 100000;           // nodes
constexpr int NE = 1600000;          // edges
constexpr int HH = 128;              // hidden
constexpr int NR = 8;                // relations
constexpr int NBIN = 782;            // ceil(NN/128) bins by dst>>7
constexpr int CAPB = 6144;           // max edges per bin on the LDS fast path

__device__ __forceinline__ unsigned short f2bf(float f) {
    unsigned b = __float_as_uint(f);
    b += 0x7fffu + ((b >> 16) & 1u);       // round-to-nearest-even
    return (unsigned short)(b >> 16);
}

// ---- fused convert: blocks [0,1152): W transpose; rest: x ----
// Wt[L][s][f][·] (bf16) from fp32 W[d][f], stored CHUNK-SWIZZLED: within each
// 256B row, 16B chunk c lands at c ^ (f&7)  (bank-conflict-free ds_read_b128
// in bigGemm while keeping global_load_lds linear — both-sides swizzle).
__global__ void convertWX(const float* __restrict__ Wr0, const float* __restrict__ Wq0,
                          const float* __restrict__ Wr1, const float* __restrict__ Wq1,
                          unsigned short* __restrict__ Wt,
                          const int* __restrict__ node_idx,
                          const float* __restrict__ emb,
                          unsigned* __restrict__ xb32) {
    if (blockIdx.x < 1152) {           // 1152*256 = 294912 = 2*9*128*128
        int o = blockIdx.x * 256 + threadIdx.x;
        int L = o / 147456;
        int rem = o - L * 147456;
        int s = rem >> 14;
        int p = rem & 16383;
        int f = p >> 7;
        int d = p & 127;
        const float* Wq = L ? Wq1 : Wq0;
        const float* Wr = L ? Wr1 : Wr0;
        float v = (s == 0) ? Wq[d * 128 + f] : Wr[((s - 1) * 128 + d) * 128 + f];
        int cs = (d >> 3) ^ (f & 7);                     // swizzled 16B-chunk idx
        Wt[(o & ~127) | (cs << 3) | (d & 7)] = f2bf(v);
    } else {
        int i = (blockIdx.x - 1152) * 256 + threadIdx.x;
        if (i >= NN * 64) return;
        int n = i >> 6, dp = i & 63;
        int row = node_idx[n];
        float2 v = *((const float2*)(emb + (size_t)row * HH) + dp);
        xb32[(size_t)n * 64 + dp] = (unsigned)f2bf(v.x) | ((unsigned)f2bf(v.y) << 16);
    }
}

// ---- pass A1: per-bin edge counts (LDS histogram -> global merge) ----
__global__ __launch_bounds__(256) void binCount(const int* __restrict__ edst,
                                                unsigned* __restrict__ binCounts) {
    __shared__ unsigned hist[NBIN];
    for (int i = threadIdx.x; i < NBIN; i += 256) hist[i] = 0;
    __syncthreads();
    int stride = gridDim.x * 256;
    for (int e = blockIdx.x * 256 + threadIdx.x; e < NE; e += stride)
        atomicAdd(&hist[((unsigned)edst[e]) >> 7], 1u);
    __syncthreads();
    for (int i = threadIdx.x; i < NBIN; i += 256)
        if (hist[i]) atomicAdd(&binCounts[i], hist[i]);
}

// ---- pass A2: exclusive scan of 782 bin counts; init cursors ----
__global__ void binScan(const unsigned* __restrict__ binCounts,
                        unsigned* __restrict__ binStarts,
                        unsigned* __restrict__ binCursor) {
    __shared__ unsigned sh[1024];
    int tid = threadIdx.x;
    unsigned v = (tid < NBIN) ? binCounts[tid] : 0u;
    sh[tid] = v;
    __syncthreads();
    for (int ofs = 1; ofs < 1024; ofs <<= 1) {
        unsigned t = (tid >= ofs) ? sh[tid - ofs] : 0u;
        __syncthreads();
        sh[tid] += t;
        __syncthreads();
    }
    if (tid < NBIN) {
        unsigned s = sh[tid] - v;
        binStarts[tid] = s;
        binCursor[tid] = s;
    }
    if (tid == 0) binStarts[NBIN] = NE;
}

// ---- pass A3: scatter edges into bins (block-chunked -> L2-local writes) ----
// payload: src(17b) | rel(3b)<<17 | dstlow(7b)<<20
__global__ __launch_bounds__(256) void binScatter(
        const int* __restrict__ esrc, const int* __restrict__ edst,
        const int* __restrict__ etype, unsigned* __restrict__ binCursor,
        unsigned* __restrict__ binned) {
    __shared__ unsigned hist[NBIN];
    __shared__ unsigned cur[NBIN];
    for (int i = threadIdx.x; i < NBIN; i += 256) hist[i] = 0;
    __syncthreads();
    int per = (NE + gridDim.x - 1) / gridDim.x;
    int lo = blockIdx.x * per;
    int hi = lo + per; if (hi > NE) hi = NE;
    for (int e = lo + threadIdx.x; e < hi; e += 256)
        atomicAdd(&hist[((unsigned)edst[e]) >> 7], 1u);
    __syncthreads();
    for (int i = threadIdx.x; i < NBIN; i += 256) {
        unsigned c = hist[i];
        cur[i] = c ? atomicAdd(&binCursor[i], c) : 0u;
    }
    __syncthreads();
    for (int e = lo + threadIdx.x; e < hi; e += 256) {
        unsigned d = (unsigned)edst[e];
        unsigned b = d >> 7;
        unsigned pos = atomicAdd(&cur[b], 1u);
        binned[pos] = (unsigned)esrc[e] | (((unsigned)etype[e]) << 17) |
                      ((d & 127u) << 20);
    }
}

// ---- pass B: per-bin LDS sort by (dstlow,rel); emit payload + CSR starts ----
// payload: src(17b)<<3 | rel(3b) | deg(12b)<<20
__global__ __launch_bounds__(256) void binSort(
        const unsigned* __restrict__ binStarts, const unsigned* __restrict__ binned,
        unsigned* __restrict__ epk, unsigned* __restrict__ starts) {
    __shared__ unsigned hist[1024];
    __shared__ unsigned scn[1024];
    __shared__ unsigned cnts[1024];
    __shared__ unsigned part[256];
    __shared__ unsigned buf[CAPB];
    __shared__ unsigned outb[CAPB];
    int bin = blockIdx.x;
    int tid = threadIdx.x;
    unsigned base = binStarts[bin];
    int cnt = (int)(binStarts[bin + 1] - base);

    for (int i = tid; i < 1024; i += 256) hist[i] = 0;
    __syncthreads();
    for (int i = tid; i < cnt; i += 256) {
        unsigned p = binned[base + i];
        if (i < CAPB) buf[i] = p;
        atomicAdd(&hist[(p >> 17) & 0x3ffu], 1u);   // key = dstlow*8 + rel
    }
    __syncthreads();
    // exclusive scan of hist[1024]
    unsigned h4[4], tsum = 0;
#pragma unroll
    for (int j = 0; j < 4; ++j) { h4[j] = hist[tid * 4 + j]; tsum += h4[j]; }
    part[tid] = tsum;
    __syncthreads();
    for (int ofs = 1; ofs < 256; ofs <<= 1) {
        unsigned t = (tid >= ofs) ? part[tid - ofs] : 0u;
        __syncthreads();
        part[tid] += t;
        __syncthreads();
    }
    unsigned run = part[tid] - tsum;
#pragma unroll
    for (int j = 0; j < 4; ++j) { scn[tid * 4 + j] = run; run += h4[j]; }
    __syncthreads();
    // global CSR starts (starts[node*8+rel] == base + scn[key]); keep counts
    for (int i = tid; i < 1024; i += 256) {
        starts[(size_t)bin * 1024 + i] = base + scn[i];
        cnts[i] = hist[i];                           // segment length for deg
        hist[i] = scn[i];                            // reuse hist as cursor
    }
    __syncthreads();
    if (cnt <= CAPB) {
        for (int i = tid; i < cnt; i += 256) {
            unsigned p = buf[i];
            unsigned key = (p >> 17) & 0x3ffu;
            unsigned pos = atomicAdd(&hist[key], 1u);
            unsigned deg = cnts[key]; if (deg > 4095u) deg = 4095u;
            outb[pos] = ((p & 0x1ffffu) << 3) | (key & 7u) | (deg << 20);
        }
        __syncthreads();
        for (int i = tid; i < cnt; i += 256) epk[base + i] = outb[i];
    } else {                                          // never expected; safety
        for (int i = tid; i < cnt; i += 256) {
            unsigned p = binned[base + i];
            unsigned key = (p >> 17) & 0x3ffu;
            unsigned pos = atomicAdd(&hist[key], 1u);
            unsigned deg = cnts[key]; if (deg > 4095u) deg = 4095u;
            epk[base + pos] = ((p & 0x1ffffu) << 3) | (key & 7u) | (deg << 20);
        }
    }
}

// ---- transform-first GEMM: y[n][r] = x[n] @ W_r, root = x @ W_root ----
// A (x rows) in 32 VGPRs; B (Wt) LDS double-buffered via global_load_lds w=16.
// LDS-transpose epilogue: 256B-granular y writes / 1KB root writes.
// (proven round-4; byte-identical)
__global__ __launch_bounds__(512, 4) void bigGemm(const unsigned short* x,
                                                  const unsigned short* __restrict__ Wt,
                                                  unsigned* __restrict__ y32,
                                                  unsigned* root32) {
    typedef __attribute__((address_space(3))) unsigned lds_u32_t;
    typedef const __attribute__((address_space(1))) unsigned glb_u32_t;
    __shared__ __align__(16) unsigned short Bl[2][16384];   // 64 KB W double-buf
    __shared__ __align__(16) unsigned Tld[64 * 64];         // 16 KB transpose buf

    int tid = threadIdx.x;
    int wid = tid >> 6, lane = tid & 63;
    int quad = lane >> 4, l16 = lane & 15;
    int wr = wid >> 1, wc = wid & 1;   // wr: node quarter (32), wc: channel half (64)
    int m0 = blockIdx.x * 128;
    int sw = l16 & 7;                  // read-side chunk swizzle for W

    auto prefetch = [&](int s, int b) {
        const char* gs = (const char*)Wt + (size_t)s * 32768 + wid * 4096 + lane * 16;
        char* ls = (char*)&Bl[b][0] + wid * 4096;
#pragma unroll
        for (int j = 0; j < 4; ++j)
            __builtin_amdgcn_global_load_lds((glb_u32_t*)(const void*)(gs + j * 1024),
                                             (lds_u32_t*)(void*)(ls + j * 1024),
                                             16, 0, 0);
    };

    prefetch(0, 0);

    // A fragments: node = m0 + wr*32 + nt*16 + l16, k = kt*32 + quad*8
    bf16x8 ax[2][4];
#pragma unroll
    for (int nt = 0; nt < 2; ++nt) {
        int node = m0 + wr * 32 + nt * 16 + l16;
        node = node < NN ? node : NN - 1;
        const unsigned short* rp = x + (size_t)node * HH + quad * 8;
#pragma unroll
        for (int kt = 0; kt < 4; ++kt)
            ax[nt][kt] = *(const bf16x8*)(rp + kt * 32);
    }
    __syncthreads();   // drains A loads + prefetch(0); covers x==root32 alias

    for (int s = 0; s < 9; ++s) {
        if (s < 8) prefetch(s + 1, (s + 1) & 1);
        const char* Bb = (const char*)&Bl[s & 1][0];

        f32x4 acc[2][4];
#pragma unroll
        for (int nt = 0; nt < 2; ++nt)
#pragma unroll
            for (int ft = 0; ft < 4; ++ft) acc[nt][ft] = (f32x4){0.f, 0.f, 0.f, 0.f};

#pragma unroll
        for (int kt = 0; kt < 4; ++kt) {
            bf16x8 bw[4];
#pragma unroll
            for (int ft = 0; ft < 4; ++ft) {
                int f = wc * 64 + ft * 16 + l16;
                bw[ft] = *(const bf16x8*)(Bb + f * 256 +
                                          (((kt * 4 + quad) ^ sw) << 4));
            }
#pragma unroll
            for (int nt = 0; nt < 2; ++nt)
#pragma unroll
                for (int ft = 0; ft < 4; ++ft)
                    acc[nt][ft] = __builtin_amdgcn_mfma_f32_16x16x32_bf16(
                        bw[ft], ax[nt][kt], acc[nt][ft], 0, 0, 0);
        }

        // transpose epilogue in two 64-row halves (h: rows h*64 .. h*64+63)
#pragma unroll
        for (int h = 0; h < 2; ++h) {
            __syncthreads();              // prev reads of Tld done; MFMA (h=0) done
            if ((wr >> 1) == h) {         // waves owning rows of this half write
#pragma unroll
                for (int nt = 0; nt < 2; ++nt) {
                    int rT = (wr & 1) * 32 + nt * 16 + l16;
#pragma unroll
                    for (int ft = 0; ft < 4; ++ft) {
                        unsigned d0, d1;
                        asm("v_cvt_pk_bf16_f32 %0, %1, %2"
                            : "=v"(d0) : "v"(acc[nt][ft][0]), "v"(acc[nt][ft][1]));
                        asm("v_cvt_pk_bf16_f32 %0, %1, %2"
                            : "=v"(d1) : "v"(acc[nt][ft][2]), "v"(acc[nt][ft][3]));
                        int slot = wc * 16 + ft * 4 + quad;     // 8B slot in row
                        *(uint2*)((char*)Tld + rT * 256 +
                                  ((slot ^ ((rT & 7) << 2)) << 3)) =
                            make_uint2(d0, d1);
                    }
                }
            }
            __syncthreads();
            // coalesced store: 8 waves x 2 passes x 4 rows = 64 rows
#pragma unroll
            for (int p = 0; p < 2; ++p) {
                int rT = p * 32 + wid * 4 + quad;
                uint4 v = *(const uint4*)((char*)Tld + rT * 256 +
                                          (((l16 * 2) ^ ((rT & 7) << 2)) << 3));
                int node = m0 + h * 64 + rT;
                if (node < NN) {
                    unsigned* dst = (s == 0) ? (root32 + (size_t)node * 64)
                                             : (y32 + ((size_t)node * 8 + (s - 1)) * 64);
                    *(uint4*)(dst + l16 * 4) = v;
                }
            }
        }
    }
}

// ---- relation-free scaled segment-sum: TWO NODES PER WAVE (32 lanes each) ----
// out[node] = relu(root[node] + b + sum_e nrm_e * y[row_e])
// Each lane covers 4 channels via dwordx2 y reads: one j-slot processes TWO
// edges (one per half) with the instruction budget that previously did one —
// VMEM insts/edge halved, bpermute/edge halved. ILP-8 batching unchanged.
__global__ __launch_bounds__(256) void scatterAgg(
        const unsigned* __restrict__ starts, const unsigned* __restrict__ epk,
        const unsigned* __restrict__ y32, const unsigned* root32,
        const float* __restrict__ bias,
        float* __restrict__ outF, unsigned* outB) {
    int lane = threadIdx.x & 63;
    int h = lane >> 5, ln = lane & 31;
    int node = blockIdx.x * 8 + ((threadIdx.x >> 6) << 1) + h;   // NN%8==0: exact

    unsigned s0 = starts[(size_t)node * 8];
    unsigned s1 = starts[(size_t)node * 8 + 8];
    int cnt = (int)(s1 - s0);
    int cnt0 = __builtin_amdgcn_readlane(cnt, 0);
    int cnt1 = __builtin_amdgcn_readlane(cnt, 32);
    int maxc = cnt0 > cnt1 ? cnt0 : cnt1;

    float a0 = 0.f, a1 = 0.f, a2 = 0.f, a3 = 0.f;
    for (int c0 = 0; c0 < maxc; c0 += 32) {
        unsigned myE = s0 + (unsigned)c0 + (unsigned)ln;
        unsigned pk = (myE < s1) ? epk[myE] : 0u;
        int cend = maxc - c0;
        if (cend > 32) cend = 32;
        for (int base = 0; base < cend; base += 8) {
            int bix = ((h << 5) | base) << 2;
            unsigned pj[8];
            uint2 qj[8];
#pragma unroll
            for (int j = 0; j < 8; ++j)
                pj[j] = (unsigned)__builtin_amdgcn_ds_bpermute(bix + (j << 2), (int)pk);
#pragma unroll
            for (int j = 0; j < 8; ++j)
                if (c0 + base + j < cnt)
                    qj[j] = *(const uint2*)(y32 +
                             ((size_t)(pj[j] & 0xFFFFFu) << 6) + ln * 2);
#pragma unroll
            for (int j = 0; j < 8; ++j) {
                if (c0 + base + j < cnt) {
                    float nr = __builtin_amdgcn_rcpf((float)(pj[j] >> 20));
                    a0 += __uint_as_float(qj[j].x << 16) * nr;
                    a1 += __uint_as_float(qj[j].x & 0xffff0000u) * nr;
                    a2 += __uint_as_float(qj[j].y << 16) * nr;
                    a3 += __uint_as_float(qj[j].y & 0xffff0000u) * nr;
                }
            }
        }
    }

    uint2 r = *(const uint2*)(root32 + (size_t)node * 64 + ln * 2);
    float4 bv = ((const float4*)bias)[ln];
    float o0 = a0 + __uint_as_float(r.x << 16) + bv.x;
    float o1 = a1 + __uint_as_float(r.x & 0xffff0000u) + bv.y;
    float o2 = a2 + __uint_as_float(r.y << 16) + bv.z;
    float o3 = a3 + __uint_as_float(r.y & 0xffff0000u) + bv.w;
    o0 = o0 > 0.f ? o0 : 0.f;
    o1 = o1 > 0.f ? o1 : 0.f;
    o2 = o2 > 0.f ? o2 : 0.f;
    o3 = o3 > 0.f ? o3 : 0.f;
    if (outF) {
        *(float4*)(outF + (size_t)node * HH + ln * 4) = make_float4(o0, o1, o2, o3);
    } else {
        unsigned d0 = (unsigned)f2bf(o0) | ((unsigned)f2bf(o1) << 16);
        unsigned d1 = (unsigned)f2bf(o2) | ((unsigned)f2bf(o3) << 16);
        *(uint2*)(outB + (size_t)node * 64 + ln * 2) = make_uint2(d0, d1);
    }
}

extern "C" void kernel_launch(void* const* d_in, const int* in_sizes, int n_in,
                              void* d_out, int out_size, void* d_ws, size_t ws_size,
                              hipStream_t stream) {
    const int* node_idx = (const int*)d_in[0];
    const int* eidx     = (const int*)d_in[1];
    const int* etype    = (const int*)d_in[2];
    const float* emb    = (const float*)d_in[3];
    const float* Wr0    = (const float*)d_in[4];
    const float* Wq0    = (const float*)d_in[5];
    const float* b0     = (const float*)d_in[6];
    const float* Wr1    = (const float*)d_in[7];
    const float* Wq1    = (const float*)d_in[8];
    const float* b1     = (const float*)d_in[9];
    const int* esrc = eidx;
    const int* edst = eidx + NE;

    char* ws = (char*)d_ws;
    size_t off = 0;
    auto alloc = [&](size_t bytes) -> void* {
        void* p = ws + off;
        off = (off + bytes + 255) & ~(size_t)255;
        return p;
    };
    // Workspace ~240.6 MB (same proven layout; y32 reuses h32's slab).
    unsigned* binCounts = (unsigned*)alloc((size_t)NBIN * 4);
    unsigned* binStarts = (unsigned*)alloc((size_t)(NBIN + 1) * 4);
    unsigned* binCursor = (unsigned*)alloc((size_t)NBIN * 4);
    unsigned* starts    = (unsigned*)alloc((size_t)NBIN * 1024 * 4);   // 3.2 MB CSR
    unsigned* epk       = (unsigned*)alloc((size_t)NE * 4);
    unsigned* xb32      = (unsigned*)alloc((size_t)NN * 64 * 4);       // x / root / out
    unsigned* y32       = (unsigned*)alloc((size_t)NN * 8 * 64 * 4);   // 204.8 MB
    unsigned short* Wt  = (unsigned short*)alloc((size_t)2 * 9 * 16384 * 2);
    unsigned* binned = y32;   // alias: y32 dead until bigGemm, binned dead after binSort
    (void)ws_size; (void)n_in; (void)in_sizes; (void)out_size;

    hipMemsetAsync(binCounts, 0, (size_t)NBIN * 4, stream);
    convertWX<<<1152 + (NN * 64 + 255) / 256, 256, 0, stream>>>(
        Wr0, Wq0, Wr1, Wq1, Wt, node_idx, emb, xb32);
    binCount<<<256, 256, 0, stream>>>(edst, binCounts);
    binScan<<<1, 1024, 0, stream>>>(binCounts, binStarts, binCursor);
    binScatter<<<128, 256, 0, stream>>>(esrc, edst, etype, binCursor, binned);
    binSort<<<NBIN, 256, 0, stream>>>(binStarts, binned, epk, starts);

    int nblk = (NN + 127) / 128;
    // layer 0: y = x@W_r, root = x@W_root (in place), then scaled segment-sum
    bigGemm<<<nblk, 512, 0, stream>>>((const unsigned short*)xb32, Wt, y32, xb32);
    scatterAgg<<<NN / 8, 256, 0, stream>>>(starts, epk, y32, xb32, b0,
                                           nullptr, xb32);
    // layer 1: same on relu output; final result fp32 to d_out
    bigGemm<<<nblk, 512, 0, stream>>>((const unsigned short*)xb32, Wt + 147456,
                                      y32, xb32);
    scatterAgg<<<NN / 8, 256, 0, stream>>>(starts, epk, y32, xb32, b1,
                                           (float*)d_out, nullptr);
}